// Round 9
// baseline (848.388 us; speedup 1.0000x reference)
//
#include <hip/hip_runtime.h>
#include <math.h>

// Problem constants (from reference)
#define Bb   8
#define Qq   64
#define Kk   256
#define Dd   256
#define Nn   (Bb * Qq)          // 512
#define GNi  0.0625f            // 1/GN
#define EPSf 1e-5f

// ---------------------------------------------------------------------------
// 64-lane wave reduction (sum), result broadcast to all lanes
__device__ __forceinline__ float wred(float x) {
#pragma unroll
    for (int off = 32; off > 0; off >>= 1)
        x += __shfl_xor(x, off, 64);
    return x;
}

// ---------------------------------------------------------------------------
// Device-scope grid barrier. All 256 blocks (512 thr, ~80KB LDS) are always
// co-resident (8 waves/blk vs 32/CU capacity), so spinning is deadlock-free.
// AGENT-scope acq_rel atomics provide cross-XCD visibility (guide §6 G16).
__device__ __forceinline__ void grid_sync(unsigned* cnt, unsigned target) {
    __syncthreads();
    if (threadIdx.x == 0) {
        __hip_atomic_fetch_add(cnt, 1u, __ATOMIC_ACQ_REL, __HIP_MEMORY_SCOPE_AGENT);
        while (__hip_atomic_load(cnt, __ATOMIC_ACQUIRE, __HIP_MEMORY_SCOPE_AGENT) < target)
            __builtin_amdgcn_s_sleep(8);
    }
    __syncthreads();
}

// ---------------------------------------------------------------------------
// 64x64 GEMM tile core for one 256-thread half-block; R regions share the A
// tile. Barrier count = 2 per k0-iter regardless of R, so two halves running
// this with the SAME Kc stay barrier-aligned. ldb hardcoded 256.
template<int R>
__device__ __forceinline__ void gemm64(
    int htid, const float* __restrict__ A, int lda,
    const float* __restrict__ B0, const float* __restrict__ B1,
    const float* __restrict__ B2, const float* __restrict__ B3,
    int bn, int Kc, float (&acc)[R][16], float* As, float* Ws)
{
    const int aRow = htid >> 2, aCol = (htid & 3) * 4;
    const int wr = htid >> 4, wcb = (htid & 15) * 4;
    const int ty = htid >> 4, tx = htid & 15;
    const float* Bp[4] = {B0, B1, B2, B3};

    float4 rA = *(const float4*)(A + (size_t)aRow * lda + aCol);
    float4 rW[R];
#pragma unroll
    for (int r = 0; r < R; ++r)
        rW[r] = *(const float4*)(Bp[r] + (size_t)wr * 256 + bn + wcb);

    for (int k0 = 0; k0 < Kc; k0 += 16) {
        __syncthreads();
        As[(aCol + 0) * 68 + aRow] = rA.x;
        As[(aCol + 1) * 68 + aRow] = rA.y;
        As[(aCol + 2) * 68 + aRow] = rA.z;
        As[(aCol + 3) * 68 + aRow] = rA.w;
#pragma unroll
        for (int r = 0; r < R; ++r)
            *(float4*)&Ws[r * 1088 + wr * 68 + wcb] = rW[r];
        __syncthreads();
        if (k0 + 16 < Kc) {
            rA = *(const float4*)(A + (size_t)aRow * lda + k0 + 16 + aCol);
#pragma unroll
            for (int r = 0; r < R; ++r)
                rW[r] = *(const float4*)(Bp[r] + (size_t)(k0 + 16 + wr) * 256 + bn + wcb);
        }
#pragma unroll
        for (int kk = 0; kk < 16; ++kk) {
            const float4 a4 = *(const float4*)&As[kk * 68 + ty * 4];
            const float av[4] = {a4.x, a4.y, a4.z, a4.w};
#pragma unroll
            for (int r = 0; r < R; ++r) {
                const float4 b4 = *(const float4*)&Ws[r * 1088 + kk * 68 + tx * 4];
                const float bw[4] = {b4.x, b4.y, b4.z, b4.w};
#pragma unroll
                for (int i = 0; i < 4; ++i)
#pragma unroll
                    for (int j = 0; j < 4; ++j)
                        acc[r][i * 4 + j] = fmaf(av[i], bw[j], acc[r][i * 4 + j]);
            }
        }
    }
}

// ---------------------------------------------------------------------------
// One 8-t tile of the reverse recurrence (r7 version: 67.7 us, VGPR 64).
__device__ __forceinline__ void tile_step8(
    const float4* buf, int thi, const float* mfs, const float4* wm,
    float ql, float kc, float vc, float pc,
    float& E0, float& E1, float& E2, float& E3, float& E4, float& o,
    float (*Pt)[68], float* sb, int lane, int tl, int qq)
{
    float vreg[8];
#pragma unroll
    for (int i = 0; i < 8; ++i) {
        const int t = thi - i;
        const float mf = mfs[t];
        const float4 kv = buf[i];
        const float kkv = (kv.x + kc) * mf;
        vreg[i] = (kv.y + vc) * mf;
        const float pre = kv.z + pc;
        const float4 w = wm[t];
        const float ls = fminf(pre, 0.f) - __logf(1.f + __expf(-fabsf(pre)));
        float dg = __expf(ls * GNi);
        dg = (mf != 0.f) ? dg : 1.f;
        const float zf = (E0 + w.x * E1) + (w.y * E2 + w.z * E3) + w.w * E4;
        Pt[i][lane] = ql * kkv * zf;
        E0 *= dg;
        E1 *= (w.x > 0.f) ? dg : 1.f;
        E2 *= (w.y > 0.f) ? dg : 1.f;
        E3 *= (w.z > 0.f) ? dg : 1.f;
        E4 *= (w.w > 0.f) ? dg : 1.f;
    }
    __builtin_amdgcn_wave_barrier();
    const float4 p0 = *(const float4*)&Pt[tl][qq * 8];
    const float4 p1 = *(const float4*)&Pt[tl][qq * 8 + 4];
    float s = ((p0.x + p0.y) + (p0.z + p0.w)) + ((p1.x + p1.y) + (p1.z + p1.w));
    s += __shfl_xor(s, 8, 64);
    s += __shfl_xor(s, 16, 64);
    s += __shfl_xor(s, 32, 64);
    sb[tl] = s;                       // same-value multi-write, benign
    __builtin_amdgcn_wave_barrier();
    const float4 s0 = *(const float4*)&sb[0];
    const float4 s1 = *(const float4*)&sb[4];
    o = fmaf(s0.x, vreg[0], o); o = fmaf(s0.y, vreg[1], o);
    o = fmaf(s0.z, vreg[2], o); o = fmaf(s0.w, vreg[3], o);
    o = fmaf(s1.x, vreg[4], o); o = fmaf(s1.y, vreg[5], o);
    o = fmaf(s1.z, vreg[6], o); o = fmaf(s1.w, vreg[7], o);
}

// ---------------------------------------------------------------------------
// Megakernel: 256 blocks x 512 threads, three phases with grid barriers.
// Phase 0: fused weights  Wg=Wg1@Wg2, W'x=W_cond@Wx (x=q,k,v), W'g, W'r;
//          plus input-only KVr, KVq8.
// Phase 1: projections    KVi=keyval@[Wk|Wv|Wg] (interleaved {k,v,pre,0}),
//          Cbi=query@[W'q|W'k|W'v|W'g] ({q,k,v,pre}), Cr=query@W'r.
// Phase 2: router + recurrence + RMSNorm + W_o. 2 n per block (half s=tid>>8).
__global__ __launch_bounds__(512) void mega(
    const float* __restrict__ query, const float* __restrict__ keyval,
    const int* __restrict__ mask, const float* __restrict__ W_cond,
    const float* __restrict__ Wq, const float* __restrict__ Wk,
    const float* __restrict__ Wv, const float* __restrict__ Wg1,
    const float* __restrict__ Wg2, const float* __restrict__ b_gk2,
    const float* __restrict__ Wr, const float* __restrict__ norm_w,
    const float* __restrict__ W_o,
    float* __restrict__ Wg, float* __restrict__ Wpq, float* __restrict__ Wpk,
    float* __restrict__ Wpv, float* __restrict__ Wpg, float* __restrict__ Wpr,
    float* __restrict__ KVq8, float* __restrict__ KVr, float* __restrict__ KVi,
    float* __restrict__ Cbi, float* __restrict__ Cr,
    unsigned* __restrict__ cnt,
    float* __restrict__ out, float* __restrict__ logits)
{
    __shared__ __align__(16) float gA[2][1088];      // As per half
    __shared__ __align__(16) float gW[2][4 * 1088];  // Ws per half
    __shared__ __align__(16) float Tst[2][64 * 16];  // W'g stage-A
    __shared__ __align__(16) float4 wm[2][Kk];
    __shared__ __align__(16) float  mfs[Kk];
    __shared__ __align__(16) float  Ptile[8][8][68];
    __shared__ __align__(16) float  sbuf[8][8];
    __shared__ __align__(16) float  onorm[2][Dd];

    const int bi = blockIdx.x;
    const int tid = threadIdx.x;
    const int s = tid >> 8;          // half 0/1 (wave-uniform)
    const int htid = tid & 255;
    const int ty = htid >> 4, tx = htid & 15;

    // ===================== Phase 0: weights + input-only =====================
    if (bi < 24) {                   // W'q/k/v : 48 paired 64x64 tiles, K=256
        const int t = 2 * bi + s;
        const float* Wm = (t < 16) ? Wq : (t < 32) ? Wk : Wv;
        float* Wpm      = (t < 16) ? Wpq : (t < 32) ? Wpk : Wpv;
        const int sub = t & 15;
        const int bm = (sub >> 2) * 64, bn = (sub & 3) * 64;
        float acc[1][16] = {};
        gemm64<1>(htid, W_cond + (size_t)bm * 256, 256, Wm, nullptr, nullptr,
                  nullptr, bn, 256, acc, gA[s], gW[s]);
#pragma unroll
        for (int i = 0; i < 4; ++i)
            *(float4*)&Wpm[(size_t)(bm + ty * 4 + i) * 256 + bn + tx * 4] =
                make_float4(acc[0][i * 4 + 0], acc[0][i * 4 + 1],
                            acc[0][i * 4 + 2], acc[0][i * 4 + 3]);
    } else if (bi < 32) {            // Wg = Wg1@Wg2 : 16 paired tiles, K=16
        const int t = 2 * (bi - 24) + s;
        const int bm = (t >> 2) * 64, bn = (t & 3) * 64;
        float acc[1][16] = {};
        gemm64<1>(htid, Wg1 + (size_t)bm * 16, 16, Wg2, nullptr, nullptr,
                  nullptr, bn, 16, acc, gA[s], gW[s]);
#pragma unroll
        for (int i = 0; i < 4; ++i)
            *(float4*)&Wg[(size_t)(bm + ty * 4 + i) * 256 + bn + tx * 4] =
                make_float4(acc[0][i * 4 + 0], acc[0][i * 4 + 1],
                            acc[0][i * 4 + 2], acc[0][i * 4 + 3]);
    } else if (bi < 40) {            // W'g = (W_cond@Wg1)@Wg2 : 16 paired
        const int t = 2 * (bi - 32) + s;
        const int bm = (t >> 2) * 64, bn = (t & 3) * 64;
        // stage A: T = W_cond[bm:bm+64,:] @ Wg1  (64x16, K=256)
        {
            const int r = htid >> 2, g = htid & 3;
            float4 a4 = make_float4(0.f, 0.f, 0.f, 0.f);
            for (int k = 0; k < 256; ++k) {
                const float a = W_cond[(size_t)(bm + r) * 256 + k];
                const float4 w4 = *(const float4*)&Wg1[(size_t)k * 16 + g * 4];
                a4.x = fmaf(a, w4.x, a4.x);
                a4.y = fmaf(a, w4.y, a4.y);
                a4.z = fmaf(a, w4.z, a4.z);
                a4.w = fmaf(a, w4.w, a4.w);
            }
            *(float4*)&Tst[s][r * 16 + g * 4] = a4;
        }
        __syncthreads();             // paired halves: same count
        // stage B: out = T @ Wg2  (64x64, K=16)
        {
            float o16[16] = {};
#pragma unroll
            for (int i16 = 0; i16 < 16; ++i16) {
                const float4 w4 = *(const float4*)&Wg2[(size_t)i16 * 256 + bn + tx * 4];
#pragma unroll
                for (int i = 0; i < 4; ++i) {
                    const float tv = Tst[s][(ty * 4 + i) * 16 + i16];
                    o16[i * 4 + 0] = fmaf(tv, w4.x, o16[i * 4 + 0]);
                    o16[i * 4 + 1] = fmaf(tv, w4.y, o16[i * 4 + 1]);
                    o16[i * 4 + 2] = fmaf(tv, w4.z, o16[i * 4 + 2]);
                    o16[i * 4 + 3] = fmaf(tv, w4.w, o16[i * 4 + 3]);
                }
            }
#pragma unroll
            for (int i = 0; i < 4; ++i)
                *(float4*)&Wpg[(size_t)(bm + ty * 4 + i) * 256 + bn + tx * 4] =
                    make_float4(o16[i * 4 + 0], o16[i * 4 + 1],
                                o16[i * 4 + 2], o16[i * 4 + 3]);
        }
    } else if (bi == 40) {           // half0: W'r = W_cond@Wr; half1: KVq8
        if (s == 0) {
            float4 a4 = make_float4(0.f, 0.f, 0.f, 0.f);
            for (int k = 0; k < 256; ++k) {
                const float a = W_cond[(size_t)htid * 256 + k];
                const float4 w4 = *(const float4*)&Wr[(size_t)k * 4];
                a4.x = fmaf(a, w4.x, a4.x);
                a4.y = fmaf(a, w4.y, a4.y);
                a4.z = fmaf(a, w4.z, a4.z);
                a4.w = fmaf(a, w4.w, a4.w);
            }
            *(float4*)&Wpr[(size_t)htid * 4] = a4;
        } else {                     // KVq8 = keyval[:,255,:]@Wq (8x256)
            float a8[8] = {};
            for (int k = 0; k < 256; ++k) {
                const float wqv = Wq[(size_t)k * 256 + htid];
#pragma unroll
                for (int b8 = 0; b8 < 8; ++b8)
                    a8[b8] = fmaf(keyval[((size_t)b8 * Kk + 255) * 256 + k], wqv, a8[b8]);
            }
#pragma unroll
            for (int b8 = 0; b8 < 8; ++b8)
                KVq8[b8 * 256 + htid] = a8[b8];
        }
    } else if (bi < 57) {            // KVr = keyval@Wr : 16 blocks, barrier-free
        const int idx = (bi - 41) * 512 + tid;   // 8192 = 2048x4
        const int row = idx >> 2, col = idx & 3;
        float a = 0.f;
        for (int k = 0; k < 256; ++k)
            a = fmaf(keyval[(size_t)row * 256 + k], Wr[(size_t)k * 4 + col], a);
        KVr[idx] = a;
    }

    grid_sync(cnt, 256);

    // ===================== Phase 1: input projections ========================
    if (bi < 80) {                   // 160 paired 64x64 K=256 tasks
        const int t = 2 * bi + s;
        if (t < 128) {               // KVi = keyval@[Wk|Wv|Wg], interleaved
            const int bm = (t >> 2) * 64, bn = (t & 3) * 64;
            float acc[3][16] = {};
            gemm64<3>(htid, keyval + (size_t)bm * 256, 256, Wk, Wv, Wg,
                      nullptr, bn, 256, acc, gA[s], gW[s]);
#pragma unroll
            for (int i = 0; i < 4; ++i) {
                const size_t rowo = (size_t)(bm + ty * 4 + i) * 1024;
#pragma unroll
                for (int j = 0; j < 4; ++j)
                    *(float4*)&KVi[rowo + (size_t)(bn + tx * 4 + j) * 4] =
                        make_float4(acc[0][i * 4 + j], acc[1][i * 4 + j],
                                    acc[2][i * 4 + j], 0.f);
            }
        } else {                     // Cbi = query@[W'q|W'k|W'v|W'g]
            const int t2 = t - 128;
            const int bm = (t2 >> 2) * 64, bn = (t2 & 3) * 64;
            float acc[4][16] = {};
            gemm64<4>(htid, query + (size_t)bm * 256, 256, Wpq, Wpk, Wpv, Wpg,
                      bn, 256, acc, gA[s], gW[s]);
#pragma unroll
            for (int i = 0; i < 4; ++i) {
                const size_t rowo = (size_t)(bm + ty * 4 + i) * 1024;
#pragma unroll
                for (int j = 0; j < 4; ++j)
                    *(float4*)&Cbi[rowo + (size_t)(bn + tx * 4 + j) * 4] =
                        make_float4(acc[0][i * 4 + j], acc[1][i * 4 + j],
                                    acc[2][i * 4 + j], acc[3][i * 4 + j]);
            }
        }
    } else if (bi < 84) {            // Cr = query@W'r : 4 blocks, barrier-free
        const int idx = (bi - 80) * 512 + tid;   // 2048 = 512x4
        const int row = idx >> 2, col = idx & 3;
        float a = 0.f;
        for (int k = 0; k < 256; ++k)
            a = fmaf(query[(size_t)row * 256 + k], Wpr[(size_t)k * 4 + col], a);
        Cr[idx] = a;
    }

    grid_sync(cnt, 512);

    // ===================== Phase 2: router + recurrence ======================
    const int n = 2 * bi + s;
    const int b = bi >> 5;           // = n >> 6
    const int j = htid;
    const int lane = tid & 63;
    const int wv = tid >> 6;         // global wave 0..7

    const float4 c4 = *(const float4*)&Cbi[(size_t)n * 1024 + j * 4];
    const float qc = c4.x, kc = c4.y, vc = c4.z;
    const float pc = c4.w + b_gk2[j];
    const float ql = KVq8[b * 256 + j] + qc;

    {
        mfs[j] = (float)mask[b * Kk + j];        // both halves: same value
        const float4 kvr = *(const float4*)&KVr[(size_t)(b * Kk + j) * 4];
        const float4 cr  = *(const float4*)&Cr[(size_t)n * 4];
        float l[4] = {kvr.x + cr.x, kvr.y + cr.y, kvr.z + cr.z, kvr.w + cr.w};
        *(float4*)(logits + ((size_t)n * Kk + j) * 4) =
            make_float4(l[0], l[1], l[2], l[3]);

        int i1 = 0;
#pragma unroll
        for (int q = 1; q < 4; ++q) if (l[q] > l[i1]) i1 = q;
        int i2 = -1;
#pragma unroll
        for (int q = 0; q < 4; ++q) {
            if (q == i1) continue;
            if (i2 < 0 || l[q] > l[i2]) i2 = q;
        }
        const float mx = fmaxf(l[i1], l[i2]);
        const float e1 = __expf(l[i1] - mx);
        const float e2 = __expf(l[i2] - mx);
        const float inv = 1.f / (e1 + e2);
        float w[4] = {0.f, 0.f, 0.f, 0.f};
        w[i1] = e1 * inv;
        w[i2] = e2 * inv;
        wm[s][j] = make_float4(w[0], w[1], w[2], w[3]);
    }
    __syncthreads();

    const float4* pkv = (const float4*)KVi + (size_t)b * Kk * 256 + j;

    float E0 = 1.f, E1 = 1.f, E2 = 1.f, E3 = 1.f, E4 = 1.f;
    float o = 0.f;
    const int tl = lane & 7, qq = lane >> 3;

    float4 bufA[8], bufB[8];
#pragma unroll
    for (int i = 0; i < 8; ++i) bufA[i] = pkv[(size_t)(255 - i) * 256];

    for (int p = 0; p < 16; ++p) {
        const int tA = 255 - 16 * p;
        const int tB = tA - 8;
#pragma unroll
        for (int i = 0; i < 8; ++i) bufB[i] = pkv[(size_t)(tB - i) * 256];
        tile_step8(bufA, tA, mfs, wm[s], ql, kc, vc, pc,
                   E0, E1, E2, E3, E4, o, Ptile[wv], sbuf[wv], lane, tl, qq);
        if (p < 15) {
#pragma unroll
            for (int i = 0; i < 8; ++i) bufA[i] = pkv[(size_t)(tB - 8 - i) * 256];
        }
        tile_step8(bufB, tB, mfs, wm[s], ql, kc, vc, pc,
                   E0, E1, E2, E3, E4, o, Ptile[wv], sbuf[wv], lane, tl, qq);
    }

    // fused RMSNorm over DV (per head = per wave)
    const float ms = wred(o * o) * (1.0f / 64.0f);
    onorm[s][j] = o * rsqrtf(ms + EPSf) * norm_w[j & 63];
    __syncthreads();

    // fused output projection: out[n,j] = onorm . W_o[:,j]
    float acc = 0.f;
#pragma unroll 8
    for (int k = 0; k < Dd; ++k)
        acc = fmaf(onorm[s][k], W_o[(size_t)k * Dd + j], acc);
    out[(size_t)n * Dd + j] = acc;
}

// ---------------------------------------------------------------------------
extern "C" void kernel_launch(void* const* d_in, const int* in_sizes, int n_in,
                              void* d_out, int out_size, void* d_ws, size_t ws_size,
                              hipStream_t stream)
{
    const float* query    = (const float*)d_in[0];   // (8,64,256)
    const float* keyval   = (const float*)d_in[1];   // (8,256,256)
    const int*   mask     = (const int*)  d_in[2];   // (8,256)
    const float* W_cond   = (const float*)d_in[3];   // (256,256)
    const float* W_q      = (const float*)d_in[4];   // (256,256)
    const float* W_k      = (const float*)d_in[5];   // (256,256)
    const float* W_v      = (const float*)d_in[6];   // (256,256)
    const float* W_gk1    = (const float*)d_in[7];   // (256,16)
    const float* W_gk2    = (const float*)d_in[8];   // (16,256)
    const float* b_gk2    = (const float*)d_in[9];   // (256,)
    const float* W_router = (const float*)d_in[10];  // (256,4)
    const float* norm_w   = (const float*)d_in[11];  // (64,)
    const float* W_o      = (const float*)d_in[12];  // (256,256)

    float* out    = (float*)d_out;        // (8,64,256) = 131072
    float* logits = out + Nn * Dd;        // (N*K, 4)   = 524288

    // workspace: barrier counter (64 B) then float regions
    unsigned* cnt = (unsigned*)d_ws;
    float* p = (float*)((char*)d_ws + 64);
    float* Wg   = p; p += Dd * Dd;                  // 65536
    float* Wpq  = p; p += Dd * Dd;
    float* Wpk  = p; p += Dd * Dd;
    float* Wpv  = p; p += Dd * Dd;
    float* Wpg  = p; p += Dd * Dd;
    float* Wpr  = p; p += Dd * 4;                   // 1024
    float* KVq8 = p; p += Bb * Dd;                  // 2048
    float* KVr  = p; p += Bb * Kk * 4;              // 8192
    float* KVi  = p; p += (size_t)Bb * Kk * 1024;   // 2097152 {k,v,pre,0}
    float* Cbi  = p; p += (size_t)Nn * 1024;        // 524288 {q,k,v,pre}
    float* Cr   = p; p += Nn * 4;                   // 2048

    // zero the grid-barrier counter (d_ws is poisoned each timed call)
    hipMemsetAsync(d_ws, 0, 64, stream);

    mega<<<256, dim3(512), 0, stream>>>(
        query, keyval, mask, W_cond, W_q, W_k, W_v, W_gk1, W_gk2, b_gk2,
        W_router, norm_w, W_o,
        Wg, Wpq, Wpk, Wpv, Wpg, Wpr, KVq8, KVr, KVi, Cbi, Cr,
        cnt, out, logits);
}